// Round 7
// baseline (1110.662 us; speedup 1.0000x reference)
//
#include <hip/hip_runtime.h>
#include <hip/hip_fp16.h>

#define N_USERS 50000
#define N_ITEMS 100000
#define N_NODES (N_USERS + N_ITEMS)
#define DIM 64
#define D2  (DIM / 2)                    // half2 per row
#define BROWS 128                        // rows per bucket
#define NB ((N_NODES + BROWS - 1) / BROWS)   // 1172 buckets
#define SLOTS 4                          // LDS line-buffer slots per bucket

// ---------------------------------------------------------------------------
// init: buf0 = fp16(concat(user, item)); bcnt = 0
// ---------------------------------------------------------------------------
__global__ void init_kernel(const float4* __restrict__ user,
                            const float4* __restrict__ item,
                            uint2* __restrict__ buf0,
                            int* __restrict__ bcnt,
                            int nUser4, int nTotal4) {
    int stride = gridDim.x * blockDim.x;
    int t0 = blockIdx.x * blockDim.x + threadIdx.x;
    for (int i = t0; i < nTotal4; i += stride) {
        float4 v = (i < nUser4) ? user[i] : item[i - nUser4];
        __half2 h0 = __floats2half2_rn(v.x, v.y);
        __half2 h1 = __floats2half2_rn(v.z, v.w);
        uint2 o;
        o.x = *(const unsigned int*)&h0;
        o.y = *(const unsigned int*)&h1;
        buf0[i] = o;
    }
    for (int i = t0; i < NB; i += stride) bcnt[i] = 0;
}

// ---------------------------------------------------------------------------
// bucket histogram: LDS-local then one global atomic per bucket per block
// ---------------------------------------------------------------------------
__global__ void hist_kernel(const int* __restrict__ rows,
                            int* __restrict__ bcnt, int nE) {
    __shared__ int h[NB];
    for (int b = threadIdx.x; b < NB; b += blockDim.x) h[b] = 0;
    __syncthreads();
    int stride = gridDim.x * blockDim.x;
    for (int i = blockIdx.x * blockDim.x + threadIdx.x; i < nE; i += stride)
        atomicAdd(&h[rows[i] >> 7], 1);
    __syncthreads();
    for (int b = threadIdx.x; b < NB; b += blockDim.x)
        if (h[b]) atomicAdd(&bcnt[b], h[b]);
}

// ---------------------------------------------------------------------------
// one-block exclusive scan of NB bucket counts (Hillis-Steele over 2048)
// writes bstart[NB+1] and gcur[NB] (= running append cursors for bin)
// ---------------------------------------------------------------------------
__global__ __launch_bounds__(1024) void scan_kernel(const int* __restrict__ bcnt,
                                                    int* __restrict__ bstart,
                                                    int* __restrict__ gcur) {
    __shared__ int a0[2048];
    __shared__ int a1[2048];
    int t = threadIdx.x;
    a0[t]        = (t < NB) ? bcnt[t] : 0;
    a0[t + 1024] = (t + 1024 < NB) ? bcnt[t + 1024] : 0;
    __syncthreads();
    int* src = a0; int* dst = a1;
    for (int off = 1; off < 2048; off <<= 1) {
        #pragma unroll
        for (int k = 0; k < 2; ++k) {
            int i = t + k * 1024;
            int v = src[i];
            if (i >= off) v += src[i - off];
            dst[i] = v;
        }
        __syncthreads();
        int* tmp = src; src = dst; dst = tmp;
    }
    #pragma unroll
    for (int k = 0; k < 2; ++k) {
        int i = t + k * 1024;
        if (i < NB) {
            int ex = (i == 0) ? 0 : src[i - 1];
            bstart[i] = ex;
            gcur[i]   = ex;
        }
    }
    if (t == 0) bstart[NB] = src[NB - 1];
}

// ---------------------------------------------------------------------------
// bin: group edges by 128-row bucket with LDS line buffers.
// Tile-synchronous: phase1 stage into sbuf (overflow -> direct append),
// phase2 (one owner thread per bucket) flushes full buffers with one
// atomic cursor bump + contiguous 32B write. Payload 8B:
//   word0 = col | (row_local << 18), word1 = f32 val.
// ---------------------------------------------------------------------------
__global__ void bin_kernel(const int* __restrict__ rows,
                           const int* __restrict__ cols,
                           const float* __restrict__ vals,
                           int* __restrict__ gcur,
                           uint2* __restrict__ ebuf, int nE) {
    __shared__ int  cnt[NB];
    __shared__ uint2 sbuf[NB][SLOTS];            // 1172*4*8B = 37.5KB
    const int T = 256;
    for (int b = threadIdx.x; b < NB; b += T) cnt[b] = 0;
    __syncthreads();
    int perBlk = (nE + gridDim.x - 1) / gridDim.x;
    int beg = blockIdx.x * perBlk;
    int end = beg + perBlk; if (end > nE) end = nE;
    for (int base = beg; base < end; base += T) {
        int e = base + threadIdx.x;
        if (e < end) {
            int   r = __builtin_nontemporal_load(rows + e);
            int   c = __builtin_nontemporal_load(cols + e);
            float v = __builtin_nontemporal_load(vals + e);
            int myb = r >> 7;
            uint2 pay;
            pay.x = (unsigned)c | ((unsigned)(r & (BROWS - 1)) << 18);
            pay.y = __float_as_uint(v);
            int pos = atomicAdd(&cnt[myb], 1);
            if (pos < SLOTS) {
                sbuf[myb][pos] = pay;
            } else {                               // rare overflow: direct
                int gi = atomicAdd(&gcur[myb], 1);
                ebuf[gi] = pay;
            }
        }
        __syncthreads();
        for (int b = threadIdx.x; b < NB; b += T) {
            if (cnt[b] >= SLOTS) {
                int gi = atomicAdd(&gcur[b], SLOTS);
                #pragma unroll
                for (int j = 0; j < SLOTS; ++j) ebuf[gi + j] = sbuf[b][j];
                cnt[b] = 0;
            }
        }
        __syncthreads();
    }
    // final partial flush
    for (int b = threadIdx.x; b < NB; b += T) {
        int k = cnt[b]; if (k > SLOTS) k = SLOTS;
        if (k > 0) {
            int gi = atomicAdd(&gcur[b], k);
            for (int j = 0; j < k; ++j) ebuf[gi + j] = sbuf[b][j];
        }
    }
}

// ---------------------------------------------------------------------------
// SpMM over one bucket per block: accumulate 128 rows x 64 dims in LDS
// (ds_add_f32), then one coalesced write per row. Half-wave (32 lanes, d2 =
// lane&31 covers the row as half2) processes 4 edges per trip for ILP.
// MODE 0: buf1[r] = fp16(sum)
// MODE 1: out[r] = (emb_fp32[r] + prev[r] + sum) / 3
// ---------------------------------------------------------------------------
template <int MODE>
__global__ __launch_bounds__(256) void spmm_bucket_kernel(
        const int* __restrict__ bstart,
        const uint2* __restrict__ ebuf,
        const __half2* __restrict__ src2,
        __half2* __restrict__ dst2,
        const float2* __restrict__ user2,
        const float2* __restrict__ item2,
        const __half2* __restrict__ prev2,
        float2* __restrict__ out2) {
    __shared__ float acc[BROWS * DIM];           // 32KB
    int b   = blockIdx.x;
    int beg = bstart[b];
    int end = bstart[b + 1];
    for (int i = threadIdx.x; i < BROWS * DIM; i += 256) acc[i] = 0.f;
    __syncthreads();

    int half_id = threadIdx.x >> 5;              // 0..7
    int d2      = threadIdx.x & 31;

    for (int i0 = beg + half_id * 4; i0 < end; i0 += 32) {
        int n = end - i0; if (n > 4) n = 4;
        if (n == 4) {
            uint2 e0 = ebuf[i0];
            uint2 e1 = ebuf[i0 + 1];
            uint2 e2 = ebuf[i0 + 2];
            uint2 e3 = ebuf[i0 + 3];
            __half2 h0 = src2[(e0.x & 0x3FFFF) * D2 + d2];
            __half2 h1 = src2[(e1.x & 0x3FFFF) * D2 + d2];
            __half2 h2 = src2[(e2.x & 0x3FFFF) * D2 + d2];
            __half2 h3 = src2[(e3.x & 0x3FFFF) * D2 + d2];
            float2 s0 = __half22float2(h0); float v0 = __uint_as_float(e0.y);
            float2 s1 = __half22float2(h1); float v1 = __uint_as_float(e1.y);
            float2 s2 = __half22float2(h2); float v2 = __uint_as_float(e2.y);
            float2 s3 = __half22float2(h3); float v3 = __uint_as_float(e3.y);
            int r0 = e0.x >> 18, r1 = e1.x >> 18, r2 = e2.x >> 18, r3 = e3.x >> 18;
            unsafeAtomicAdd(&acc[r0 * DIM + d2 * 2],     v0 * s0.x);
            unsafeAtomicAdd(&acc[r0 * DIM + d2 * 2 + 1], v0 * s0.y);
            unsafeAtomicAdd(&acc[r1 * DIM + d2 * 2],     v1 * s1.x);
            unsafeAtomicAdd(&acc[r1 * DIM + d2 * 2 + 1], v1 * s1.y);
            unsafeAtomicAdd(&acc[r2 * DIM + d2 * 2],     v2 * s2.x);
            unsafeAtomicAdd(&acc[r2 * DIM + d2 * 2 + 1], v2 * s2.y);
            unsafeAtomicAdd(&acc[r3 * DIM + d2 * 2],     v3 * s3.x);
            unsafeAtomicAdd(&acc[r3 * DIM + d2 * 2 + 1], v3 * s3.y);
        } else {
            for (int j = 0; j < n; ++j) {
                uint2 e0 = ebuf[i0 + j];
                float2 s0 = __half22float2(src2[(e0.x & 0x3FFFF) * D2 + d2]);
                float v0 = __uint_as_float(e0.y);
                int r0 = e0.x >> 18;
                unsafeAtomicAdd(&acc[r0 * DIM + d2 * 2],     v0 * s0.x);
                unsafeAtomicAdd(&acc[r0 * DIM + d2 * 2 + 1], v0 * s0.y);
            }
        }
    }
    __syncthreads();

    int rowbase = b * BROWS;
    for (int idx = threadIdx.x; idx < BROWS * D2; idx += 256) {
        int rl = idx >> 5, col = idx & 31;
        int r = rowbase + rl;
        if (r < N_NODES) {
            float ax = acc[rl * DIM + col * 2];
            float ay = acc[rl * DIM + col * 2 + 1];
            size_t o = (size_t)r * D2 + col;
            if (MODE == 0) {
                dst2[o] = __floats2half2_rn(ax, ay);
            } else {
                float2 emb = (r < N_USERS) ? user2[o]
                                           : item2[o - (size_t)N_USERS * D2];
                float2 p = __half22float2(prev2[o]);
                out2[o] = make_float2((emb.x + p.x + ax) * (1.0f / 3.0f),
                                      (emb.y + p.y + ay) * (1.0f / 3.0f));
            }
        }
    }
}

extern "C" void kernel_launch(void* const* d_in, const int* in_sizes, int n_in,
                              void* d_out, int out_size, void* d_ws, size_t ws_size,
                              hipStream_t stream) {
    const float* user = (const float*)d_in[0];
    const float* item = (const float*)d_in[1];
    const int*   rows = (const int*)d_in[2];
    const int*   cols = (const int*)d_in[3];
    const float* vals = (const float*)d_in[4];
    float* out = (float*)d_out;

    const int    nEdges = in_sizes[2];
    const size_t nNodeF = (size_t)N_NODES * DIM;

    // workspace: buf0(half) | buf1(half) | ebuf(uint2 E) | bcnt | bstart | gcur
    __half* buf0   = (__half*)d_ws;
    __half* buf1   = buf0 + nNodeF;
    uint2*  ebuf   = (uint2*)(buf1 + nNodeF);
    int*    bcnt   = (int*)(ebuf + nEdges);
    int*    bstart = bcnt + NB;
    int*    gcur   = bstart + NB + 1;

    const int n4     = (int)(nNodeF / 4);
    const int nUser4 = N_USERS * DIM / 4;

    // 1. buf0 = fp16(emb); bcnt = 0
    init_kernel<<<256, 256, 0, stream>>>((const float4*)user, (const float4*)item,
                                         (uint2*)buf0, bcnt, nUser4, n4);
    // 2. bucket histogram
    hist_kernel<<<128, 256, 0, stream>>>(rows, bcnt, nEdges);
    // 3. scan -> bstart, gcur
    scan_kernel<<<1, 1024, 0, stream>>>(bcnt, bstart, gcur);
    // 4. bucket-bin edges
    bin_kernel<<<128, 256, 0, stream>>>(rows, cols, vals, gcur, ebuf, nEdges);
    // 5. e1 = A @ emb -> buf1 (fp16)
    spmm_bucket_kernel<0><<<NB, 256, 0, stream>>>(bstart, ebuf,
                                                  (const __half2*)buf0,
                                                  (__half2*)buf1,
                                                  nullptr, nullptr, nullptr,
                                                  nullptr);
    // 6. out = (emb_fp32 + e1 + A @ e1) / 3
    spmm_bucket_kernel<1><<<NB, 256, 0, stream>>>(bstart, ebuf,
                                                  (const __half2*)buf1,
                                                  nullptr,
                                                  (const float2*)user,
                                                  (const float2*)item,
                                                  (const __half2*)buf1,
                                                  (float2*)out);
}

// Round 9
// 248.443 us; speedup vs baseline: 4.4705x; 4.4705x over previous
//
#include <hip/hip_runtime.h>
#include <hip/hip_fp16.h>

#define N_USERS 50000
#define N_ITEMS 100000
#define N_NODES (N_USERS + N_ITEMS)      // 150000
#define DIM 64
#define D2  (DIM / 2)                    // half2 per row
#define NCB 64                           // coarse buckets
#define CROWS ((N_NODES + NCB - 1) / NCB)    // 2344 rows per bucket (last: 2328)
#define CAP 24576                        // temp capacity per coarse bucket (avg 18752)
#define CHUNK 4096                       // edges per binA block
#define SC 10                            // scan items per thread in binB (256*10 >= 2344)

// ---------------------------------------------------------------------------
// init: buf0 = fp16(concat(user, item)); gcur[b] = b*CAP
// ---------------------------------------------------------------------------
__global__ void init_kernel(const float4* __restrict__ user,
                            const float4* __restrict__ item,
                            uint2* __restrict__ buf0,
                            int* __restrict__ gcur,
                            int nUser4, int nTotal4) {
    int stride = gridDim.x * blockDim.x;
    int t0 = blockIdx.x * blockDim.x + threadIdx.x;
    for (int i = t0; i < nTotal4; i += stride) {
        float4 v = (i < nUser4) ? user[i] : item[i - nUser4];
        __half2 h0 = __floats2half2_rn(v.x, v.y);
        __half2 h1 = __floats2half2_rn(v.z, v.w);
        uint2 o;
        o.x = *(const unsigned int*)&h0;
        o.y = *(const unsigned int*)&h1;
        buf0[i] = o;
    }
    for (int i = t0; i < NCB; i += stride) gcur[i] = i * CAP;
}

// ---------------------------------------------------------------------------
// binA: per-4096-edge chunk LDS counting sort by coarse bucket (r/CROWS),
// then append each bucket's run (~64 edges) to its private temp region with
// ONE cursor bump + coalesced 8B*len write. Payload: x = col | rlocal<<18,
// y = val bits (col < 2^18, rlocal < 2344 < 2^12).
// ---------------------------------------------------------------------------
__global__ __launch_bounds__(256) void binA_kernel(const int* __restrict__ rows,
                                                   const int* __restrict__ cols,
                                                   const float* __restrict__ vals,
                                                   int* __restrict__ gcur,
                                                   uint2* __restrict__ temp, int nE) {
    __shared__ uint2 stage[CHUNK];                  // 32KB
    __shared__ int hist[NCB], off0[NCB], cur[NCB], gbase[NCB];
    int beg = blockIdx.x * CHUNK;
    int end = beg + CHUNK; if (end > nE) end = nE;
    for (int b = threadIdx.x; b < NCB; b += 256) hist[b] = 0;
    __syncthreads();
    // pass 1: count coarse buckets
    for (int i = beg + threadIdx.x; i < end; i += 256) {
        int r = __builtin_nontemporal_load(rows + i);
        atomicAdd(&hist[r / CROWS], 1);
    }
    __syncthreads();
    if (threadIdx.x == 0) {
        int s = 0;
        for (int b = 0; b < NCB; ++b) { off0[b] = s; cur[b] = s; s += hist[b]; }
    }
    __syncthreads();
    // pass 2: place into stage, sorted by bucket (rows re-read: L2-hot)
    for (int i = beg + threadIdx.x; i < end; i += 256) {
        int   r = rows[i];
        int   c = __builtin_nontemporal_load(cols + i);
        float v = __builtin_nontemporal_load(vals + i);
        int  cb = r / CROWS;
        int pos = atomicAdd(&cur[cb], 1);
        uint2 p;
        p.x = (unsigned)c | ((unsigned)(r - cb * CROWS) << 18);
        p.y = __float_as_uint(v);
        stage[pos] = p;
    }
    __syncthreads();
    for (int b = threadIdx.x; b < NCB; b += 256)
        gbase[b] = hist[b] ? atomicAdd(&gcur[b], hist[b]) : 0;
    __syncthreads();
    // flush: wave-parallel coalesced run copies
    int wv = threadIdx.x >> 6, ln = threadIdx.x & 63;
    for (int b = wv; b < NCB; b += 4) {
        int len = hist[b], o0 = off0[b], gb = gbase[b];
        for (int j = ln; j < len; j += 64) temp[gb + j] = stage[o0 + j];
    }
}

// ---------------------------------------------------------------------------
// binB: one block per coarse bucket. Count local rows in LDS, exclusive-scan
// (per-thread chunks + block scan), emit row_start, then place edges at exact
// CSR positions. The write window is ~150KB -> L2 line merging. Output edge
// format: float2{col_as_int_bits, val}. Guard: last bucket has 2328 rows.
// ---------------------------------------------------------------------------
__global__ __launch_bounds__(256) void binB_kernel(const int* __restrict__ gcur,
                                                   const uint2* __restrict__ temp,
                                                   float2* __restrict__ ebuf,
                                                   int* __restrict__ row_start) {
    __shared__ int rcnt[CROWS];                    // 9.4KB
    __shared__ int rcur[CROWS];                    // 9.4KB
    __shared__ int partial[256];
    __shared__ int csum[NCB];
    __shared__ int cstart_s;
    int b = blockIdx.x;
    int t = threadIdx.x;
    if (t < NCB) csum[t] = gcur[t] - t * CAP;      // final counts per bucket
    __syncthreads();
    if (t == 0) {
        int s = 0;
        for (int j = 0; j < b; ++j) s += csum[j];
        cstart_s = s;
    }
    for (int i = t; i < CROWS; i += 256) rcnt[i] = 0;
    __syncthreads();
    int cnt_b  = csum[b];
    int cstart = cstart_s;
    int base   = b * CAP;
    // count local rows
    for (int i = t; i < cnt_b; i += 256)
        atomicAdd(&rcnt[temp[base + i].x >> 18], 1);
    __syncthreads();
    // exclusive scan of rcnt: per-thread sequential + block scan of partials
    int s = 0;
    #pragma unroll
    for (int k = 0; k < SC; ++k) {
        int idx = t * SC + k;
        if (idx < CROWS) { int v = rcnt[idx]; rcnt[idx] = s; s += v; }
    }
    partial[t] = s;
    __syncthreads();
    if (t == 0) {
        int s2 = 0;
        for (int j = 0; j < 256; ++j) { int v = partial[j]; partial[j] = s2; s2 += v; }
    }
    __syncthreads();
    int add = partial[t];
    #pragma unroll
    for (int k = 0; k < SC; ++k) {
        int idx = t * SC + k;
        if (idx < CROWS) rcnt[idx] += add;
    }
    __syncthreads();
    // emit row_start + init cursors (guard: global row may exceed N_NODES-1
    // only in the last bucket's tail; don't write past row_start[N_NODES])
    for (int i = t; i < CROWS; i += 256) {
        int gr = b * CROWS + i;
        if (gr < N_NODES) row_start[gr] = cstart + rcnt[i];
        rcur[i] = rcnt[i];
    }
    if (b == NCB - 1 && t == 0) row_start[N_NODES] = cstart + cnt_b;
    __syncthreads();
    // place at exact CSR positions (L2-merged window)
    for (int i = t; i < cnt_b; i += 256) {
        uint2 p  = temp[base + i];
        int   rl = p.x >> 18;
        int  pos = cstart + atomicAdd(&rcur[rl], 1);
        ebuf[pos] = make_float2(__int_as_float((int)(p.x & 0x3FFFF)),
                                __uint_as_float(p.y));
    }
}

// ---------------------------------------------------------------------------
// CSR SpMM, gather form, 2 rows per wave: lane = (half, d2), half-wave of 32
// lanes covers one row as 32 x half2. Sized unroll blocks 8/4/2/1.
// MODE 0: dst2[r] = fp16(sum)
// MODE 1: out2[r] = (emb_fp32[r] + prev[r] + sum) / 3
// ---------------------------------------------------------------------------
#define GBLOCK2(U)                                                             \
    {                                                                          \
        float2 ev[U];                                                          \
        _Pragma("unroll") for (int j = 0; j < U; ++j) ev[j] = edges[i + j];    \
        __half2 sv[U];                                                         \
        _Pragma("unroll") for (int j = 0; j < U; ++j)                          \
            sv[j] = src2[(size_t)__float_as_int(ev[j].x) * D2 + d2];           \
        _Pragma("unroll") for (int j = 0; j < U; ++j) {                        \
            float2 s = __half22float2(sv[j]);                                  \
            acc.x = fmaf(ev[j].y, s.x, acc.x);                                 \
            acc.y = fmaf(ev[j].y, s.y, acc.y);                                 \
        }                                                                      \
        i += U;                                                                \
    }

template <int MODE>
__global__ void spmm_csr2_kernel(const int* __restrict__ row_start,
                                 const int* __restrict__ row_end,
                                 const float2* __restrict__ edges,
                                 const __half2* __restrict__ src2,
                                 __half2* __restrict__ dst2,
                                 const float2* __restrict__ user2,
                                 const float2* __restrict__ item2,
                                 const __half2* __restrict__ prev2,
                                 float2* __restrict__ out2) {
    int wave = (blockIdx.x * blockDim.x + threadIdx.x) >> 6;
    int lane = threadIdx.x & 63;
    int half = lane >> 5;
    int d2   = lane & 31;
    int row  = wave * 2 + half;
    if (row >= N_NODES) return;
    int i   = row_start[row];
    int end = row_end[row];
    float2 acc = make_float2(0.f, 0.f);

    while (end - i >= 8) GBLOCK2(8)
    if (end - i >= 4)    GBLOCK2(4)
    if (end - i >= 2)    GBLOCK2(2)
    if (end - i >= 1)    GBLOCK2(1)

    size_t o = (size_t)row * D2 + d2;
    if (MODE == 0) {
        dst2[o] = __floats2half2_rn(acc.x, acc.y);
    } else {
        float2 emb = (row < N_USERS) ? user2[o]
                                     : item2[o - (size_t)N_USERS * D2];
        float2 p = __half22float2(prev2[o]);
        out2[o] = make_float2((emb.x + p.x + acc.x) * (1.0f / 3.0f),
                              (emb.y + p.y + acc.y) * (1.0f / 3.0f));
    }
}

extern "C" void kernel_launch(void* const* d_in, const int* in_sizes, int n_in,
                              void* d_out, int out_size, void* d_ws, size_t ws_size,
                              hipStream_t stream) {
    const float* user = (const float*)d_in[0];
    const float* item = (const float*)d_in[1];
    const int*   rows = (const int*)d_in[2];
    const int*   cols = (const int*)d_in[3];
    const float* vals = (const float*)d_in[4];
    float* out = (float*)d_out;

    const int    nEdges = in_sizes[2];
    const size_t nNodeF = (size_t)N_NODES * DIM;      // 9.6M elements

    // workspace: buf0(half) | buf1(half) | ebuf(float2 E) | temp(uint2 64*CAP)
    //            | gcur(64) | row_start(N+1)
    __half* buf0      = (__half*)d_ws;
    __half* buf1      = buf0 + nNodeF;
    float2* ebuf      = (float2*)(buf1 + nNodeF);
    uint2*  temp      = (uint2*)(ebuf + nEdges);
    int*    gcur      = (int*)(temp + (size_t)NCB * CAP);
    int*    row_start = gcur + NCB;

    const int n4      = (int)(nNodeF / 4);
    const int nUser4  = N_USERS * DIM / 4;
    const int aBlocks = (nEdges + CHUNK - 1) / CHUNK; // 293
    const int nWaves  = (N_NODES + 1) / 2;            // 2 rows per wave
    const int spmmBlocks = (nWaves + 3) / 4;          // 4 waves/block

    // 1. buf0 = fp16(emb); gcur[b] = b*CAP
    init_kernel<<<512, 256, 0, stream>>>((const float4*)user, (const float4*)item,
                                         (uint2*)buf0, gcur, nUser4, n4);
    // 2. coarse counting-sort (coalesced appends)
    binA_kernel<<<aBlocks, 256, 0, stream>>>(rows, cols, vals, gcur, temp, nEdges);
    // 3. exact CSR within each coarse bucket (L2-merged window) + row_start
    binB_kernel<<<NCB, 256, 0, stream>>>(gcur, temp, ebuf, row_start);
    // 4. e1 = A @ emb -> buf1 (fp16)
    spmm_csr2_kernel<0><<<spmmBlocks, 256, 0, stream>>>(row_start, row_start + 1,
                                                        ebuf,
                                                        (const __half2*)buf0,
                                                        (__half2*)buf1,
                                                        nullptr, nullptr, nullptr,
                                                        nullptr);
    // 5. out = (emb_fp32 + e1 + A @ e1) / 3
    spmm_csr2_kernel<1><<<spmmBlocks, 256, 0, stream>>>(row_start, row_start + 1,
                                                        ebuf,
                                                        (const __half2*)buf1,
                                                        nullptr,
                                                        (const float2*)user,
                                                        (const float2*)item,
                                                        (const __half2*)buf1,
                                                        (float2*)out);
}

// Round 10
// 208.836 us; speedup vs baseline: 5.3183x; 1.1897x over previous
//
#include <hip/hip_runtime.h>
#include <hip/hip_fp16.h>

#define N_USERS 50000
#define N_ITEMS 100000
#define N_NODES (N_USERS + N_ITEMS)      // 150000
#define DIM 64
#define NCB 256                          // coarse buckets
#define CROWS ((N_NODES + NCB - 1) / NCB)    // 586 rows per bucket (last: 570)
#define CAP 6144                         // temp capacity per bucket (avg 4688, sigma~68)
#define CHUNK 4096                       // edges per binA block

// ---------------------------------------------------------------------------
// init: buf0 = fp16(concat(user, item)); gcur[b] = b*CAP
// ---------------------------------------------------------------------------
__global__ void init_kernel(const float4* __restrict__ user,
                            const float4* __restrict__ item,
                            uint2* __restrict__ buf0,
                            int* __restrict__ gcur,
                            int nUser4, int nTotal4) {
    int stride = gridDim.x * blockDim.x;
    int t0 = blockIdx.x * blockDim.x + threadIdx.x;
    for (int i = t0; i < nTotal4; i += stride) {
        float4 v = (i < nUser4) ? user[i] : item[i - nUser4];
        __half2 h0 = __floats2half2_rn(v.x, v.y);
        __half2 h1 = __floats2half2_rn(v.z, v.w);
        uint2 o;
        o.x = *(const unsigned int*)&h0;
        o.y = *(const unsigned int*)&h1;
        buf0[i] = o;
    }
    for (int i = t0; i < NCB; i += stride) gcur[i] = i * CAP;
}

// ---------------------------------------------------------------------------
// binA: per-4096-edge chunk LDS counting sort by coarse bucket (r/CROWS),
// then append each bucket's run (~16 edges) to its private temp region with
// ONE cursor bump + coalesced writes. Payload: x = col | rlocal<<18,
// y = val bits (col < 2^18, rlocal < 586 < 2^10).
// ---------------------------------------------------------------------------
__global__ __launch_bounds__(256) void binA_kernel(const int* __restrict__ rows,
                                                   const int* __restrict__ cols,
                                                   const float* __restrict__ vals,
                                                   int* __restrict__ gcur,
                                                   uint2* __restrict__ temp, int nE) {
    __shared__ uint2 stage[CHUNK];                  // 32KB
    __shared__ int hist[NCB], off0[NCB], cur[NCB], gbase[NCB];
    __shared__ int s0[NCB], s1[NCB];
    int t = threadIdx.x;
    int beg = blockIdx.x * CHUNK;
    int end = beg + CHUNK; if (end > nE) end = nE;
    hist[t] = 0;                                    // NCB == blockDim == 256
    __syncthreads();
    // pass 1: count coarse buckets
    for (int i = beg + t; i < end; i += 256) {
        int r = __builtin_nontemporal_load(rows + i);
        atomicAdd(&hist[r / CROWS], 1);
    }
    __syncthreads();
    // parallel exclusive scan of hist (Hillis-Steele, double buffer)
    s0[t] = hist[t];
    __syncthreads();
    int* sA = s0; int* sB = s1;
    for (int off = 1; off < NCB; off <<= 1) {
        int v = sA[t] + (t >= off ? sA[t - off] : 0);
        sB[t] = v;
        __syncthreads();
        int* tmp = sA; sA = sB; sB = tmp;
    }
    off0[t] = sA[t] - hist[t];
    cur[t]  = off0[t];
    __syncthreads();
    // pass 2: place into stage, sorted by bucket (rows re-read: L2-hot)
    for (int i = beg + t; i < end; i += 256) {
        int   r = rows[i];
        int   c = __builtin_nontemporal_load(cols + i);
        float v = __builtin_nontemporal_load(vals + i);
        int  cb = r / CROWS;
        int pos = atomicAdd(&cur[cb], 1);
        uint2 p;
        p.x = (unsigned)c | ((unsigned)(r - cb * CROWS) << 18);
        p.y = __float_as_uint(v);
        stage[pos] = p;
    }
    __syncthreads();
    gbase[t] = hist[t] ? atomicAdd(&gcur[t], hist[t]) : 0;
    __syncthreads();
    // flush: half-wave-parallel coalesced run copies (runs avg ~16)
    int hw = t >> 5, ln = t & 31;
    for (int b = hw; b < NCB; b += 8) {
        int len = hist[b], o0 = off0[b], gb = gbase[b];
        for (int j = ln; j < len; j += 32) temp[gb + j] = stage[o0 + j];
    }
}

// ---------------------------------------------------------------------------
// binB: one 512-thread block per coarse bucket. Count local rows in LDS,
// parallel exclusive scan, emit row_start, place edges at exact CSR
// positions (write window ~37KB -> full L2 line merging).
// Output edge format: float2{col_as_int_bits, val}.
// ---------------------------------------------------------------------------
__global__ __launch_bounds__(512) void binB_kernel(const int* __restrict__ gcur,
                                                   const uint2* __restrict__ temp,
                                                   float2* __restrict__ ebuf,
                                                   int* __restrict__ row_start) {
    __shared__ int rcnt[CROWS];
    __shared__ int rcur[CROWS];
    __shared__ int p0[512], p1[512];
    __shared__ int cs0[NCB], cs1[NCB];
    int b = blockIdx.x;
    int t = threadIdx.x;
    // bucket counts -> inclusive scan (for cstart / cnt_b)
    if (t < NCB) cs0[t] = gcur[t] - t * CAP;
    __syncthreads();
    int* cA = cs0; int* cB = cs1;
    for (int off = 1; off < NCB; off <<= 1) {
        int v = 0;
        if (t < NCB) v = cA[t] + (t >= off ? cA[t - off] : 0);
        if (t < NCB) cB[t] = v;
        __syncthreads();
        int* tmp = cA; cA = cB; cB = tmp;
    }
    int cstart = (b == 0) ? 0 : cA[b - 1];
    int cnt_b  = cA[b] - cstart;
    for (int i = t; i < CROWS; i += 512) rcnt[i] = 0;
    __syncthreads();
    int base = b * CAP;
    // count local rows
    for (int i = t; i < cnt_b; i += 512)
        atomicAdd(&rcnt[temp[base + i].x >> 18], 1);
    __syncthreads();
    // exclusive scan of rcnt: 2 items/thread serial + parallel scan of partials
    int s = 0;
    #pragma unroll
    for (int k = 0; k < 2; ++k) {
        int idx = t * 2 + k;
        if (idx < CROWS) { int v = rcnt[idx]; rcnt[idx] = s; s += v; }
    }
    p0[t] = s;
    __syncthreads();
    int* pA = p0; int* pB = p1;
    for (int off = 1; off < 512; off <<= 1) {
        int v = pA[t] + (t >= off ? pA[t - off] : 0);
        pB[t] = v;
        __syncthreads();
        int* tmp = pA; pA = pB; pB = tmp;
    }
    int add = (t == 0) ? 0 : pA[t - 1];
    #pragma unroll
    for (int k = 0; k < 2; ++k) {
        int idx = t * 2 + k;
        if (idx < CROWS) rcnt[idx] += add;
    }
    __syncthreads();
    // emit row_start + init cursors (last bucket has 570 rows)
    for (int i = t; i < CROWS; i += 512) {
        int gr = b * CROWS + i;
        if (gr < N_NODES) row_start[gr] = cstart + rcnt[i];
        rcur[i] = rcnt[i];
    }
    if (b == NCB - 1 && t == 0) row_start[N_NODES] = cstart + cnt_b;
    __syncthreads();
    // place at exact CSR positions (L2-merged ~37KB window)
    for (int i = t; i < cnt_b; i += 512) {
        uint2 p  = temp[base + i];
        int   rl = p.x >> 18;
        int  pos = cstart + atomicAdd(&rcur[rl], 1);
        ebuf[pos] = make_float2(__int_as_float((int)(p.x & 0x3FFFF)),
                                __uint_as_float(p.y));
    }
}

// ---------------------------------------------------------------------------
// CSR SpMM, gather form, 4 rows per wave: 16 lanes per row, each lane holds
// 4 halfs (uint2). 2x the outstanding gathers per wave vs 2-row variant.
// Sized unroll blocks 8/4/2/1.
// MODE 0: dst4[r] = fp16(sum)
// MODE 1: out4[r] = (emb_fp32[r] + prev[r] + sum) / 3
// ---------------------------------------------------------------------------
#define GBLOCK4(U)                                                             \
    {                                                                          \
        float2 ev[U];                                                          \
        _Pragma("unroll") for (int j = 0; j < U; ++j) ev[j] = edges[i + j];    \
        uint2 sv[U];                                                           \
        _Pragma("unroll") for (int j = 0; j < U; ++j)                          \
            sv[j] = src4[(size_t)__float_as_int(ev[j].x) * 16 + l16];          \
        _Pragma("unroll") for (int j = 0; j < U; ++j) {                        \
            float2 a0 = __half22float2(*(__half2*)&sv[j].x);                   \
            float2 a1 = __half22float2(*(__half2*)&sv[j].y);                   \
            float v = ev[j].y;                                                 \
            acc.x = fmaf(v, a0.x, acc.x);                                      \
            acc.y = fmaf(v, a0.y, acc.y);                                      \
            acc.z = fmaf(v, a1.x, acc.z);                                      \
            acc.w = fmaf(v, a1.y, acc.w);                                      \
        }                                                                      \
        i += U;                                                                \
    }

template <int MODE>
__global__ void spmm_csr4_kernel(const int* __restrict__ row_start,
                                 const float2* __restrict__ edges,
                                 const uint2* __restrict__ src4,
                                 uint2* __restrict__ dst4,
                                 const float4* __restrict__ user4,
                                 const float4* __restrict__ item4,
                                 const uint2* __restrict__ prev4,
                                 float4* __restrict__ out4) {
    int wave = (blockIdx.x * blockDim.x + threadIdx.x) >> 6;
    int lane = threadIdx.x & 63;
    int sub  = lane >> 4;                 // 0..3: row within wave
    int l16  = lane & 15;                 // uint2 index within row
    int row  = wave * 4 + sub;
    if (row >= N_NODES) return;
    int i   = row_start[row];
    int end = row_start[row + 1];
    float4 acc = make_float4(0.f, 0.f, 0.f, 0.f);

    while (end - i >= 8) GBLOCK4(8)
    if (end - i >= 4)    GBLOCK4(4)
    if (end - i >= 2)    GBLOCK4(2)
    if (end - i >= 1)    GBLOCK4(1)

    size_t o = (size_t)row * 16 + l16;
    if (MODE == 0) {
        __half2 h0 = __floats2half2_rn(acc.x, acc.y);
        __half2 h1 = __floats2half2_rn(acc.z, acc.w);
        uint2 p;
        p.x = *(unsigned*)&h0;
        p.y = *(unsigned*)&h1;
        dst4[o] = p;
    } else {
        float4 emb = (row < N_USERS) ? user4[o]
                                     : item4[o - (size_t)N_USERS * 16];
        uint2 pv = prev4[o];
        float2 q0 = __half22float2(*(__half2*)&pv.x);
        float2 q1 = __half22float2(*(__half2*)&pv.y);
        const float s = 1.0f / 3.0f;
        out4[o] = make_float4((emb.x + q0.x + acc.x) * s,
                              (emb.y + q0.y + acc.y) * s,
                              (emb.z + q1.x + acc.z) * s,
                              (emb.w + q1.y + acc.w) * s);
    }
}

extern "C" void kernel_launch(void* const* d_in, const int* in_sizes, int n_in,
                              void* d_out, int out_size, void* d_ws, size_t ws_size,
                              hipStream_t stream) {
    const float* user = (const float*)d_in[0];
    const float* item = (const float*)d_in[1];
    const int*   rows = (const int*)d_in[2];
    const int*   cols = (const int*)d_in[3];
    const float* vals = (const float*)d_in[4];
    float* out = (float*)d_out;

    const int    nEdges = in_sizes[2];
    const size_t nNodeF = (size_t)N_NODES * DIM;      // 9.6M elements

    // workspace: buf0(half) | buf1(half) | ebuf(float2 E) | temp(uint2 NCB*CAP)
    //            | gcur(NCB) | row_start(N+1)
    __half* buf0      = (__half*)d_ws;
    __half* buf1      = buf0 + nNodeF;
    float2* ebuf      = (float2*)(buf1 + nNodeF);
    uint2*  temp      = (uint2*)(ebuf + nEdges);
    int*    gcur      = (int*)(temp + (size_t)NCB * CAP);
    int*    row_start = gcur + NCB;

    const int n4      = (int)(nNodeF / 4);
    const int nUser4  = N_USERS * DIM / 4;
    const int aBlocks = (nEdges + CHUNK - 1) / CHUNK; // 293
    const int nWaves  = (N_NODES + 3) / 4;            // 4 rows per wave
    const int spmmBlocks = (nWaves + 3) / 4;          // 4 waves/block

    // 1. buf0 = fp16(emb); gcur[b] = b*CAP
    init_kernel<<<512, 256, 0, stream>>>((const float4*)user, (const float4*)item,
                                         (uint2*)buf0, gcur, nUser4, n4);
    // 2. coarse counting-sort (coalesced appends)
    binA_kernel<<<aBlocks, 256, 0, stream>>>(rows, cols, vals, gcur, temp, nEdges);
    // 3. exact CSR within each coarse bucket (L2-merged window) + row_start
    binB_kernel<<<NCB, 512, 0, stream>>>(gcur, temp, ebuf, row_start);
    // 4. e1 = A @ emb -> buf1 (fp16)
    spmm_csr4_kernel<0><<<spmmBlocks, 256, 0, stream>>>(row_start, ebuf,
                                                        (const uint2*)buf0,
                                                        (uint2*)buf1,
                                                        nullptr, nullptr, nullptr,
                                                        nullptr);
    // 5. out = (emb_fp32 + e1 + A @ e1) / 3
    spmm_csr4_kernel<1><<<spmmBlocks, 256, 0, stream>>>(row_start, ebuf,
                                                        (const uint2*)buf1,
                                                        nullptr,
                                                        (const float4*)user,
                                                        (const float4*)item,
                                                        (const uint2*)buf1,
                                                        (float4*)out);
}